// Round 7
// baseline (114.007 us; speedup 1.0000x reference)
//
#include <hip/hip_runtime.h>

// Reference: out[b,h,w,i] = in[b, h + i/8, w + i%8, 0]
//   in : (8, 512, 512, 1) f32   (8.4 MB)
//   out: (8, 505, 505, 64) f32  (522 MB -> write-BW bound)
//
// Ladder: R2 grid-stride + 4-scalar-load + NT store = 97.4 us (5.36 TB/s)
//         R3 row-block + unaligned-16B-load + NT    = 108.8 us
//         R4 grid-stride + 4-scalar-load + plain    = 143.7 us (L1/L2 thrash)
//         R5 row-block + 4-scalar-load + NT         = 107.6 us (write scatter)
//         R6 row-block + LDS stage + plain          = 104.2 us (plain>NT, but scatter)
// R7: grid-stride over 8KB TILES + LDS stage + plain stores.
//   - dense collective write window (~16 MB) like R2/fill kernel
//   - read-free store phase like R6 (no L2-thrash on reads)
//   Tile = one 32-pixel segment of an output row: stage 8 rows x 40 floats,
//   staging writes sequential (conflict-free), reads (8r+c+p)%32 -> exactly
//   2 lanes/bank (free, m136).

#define BATCH   8
#define W_IN    512
#define HW_OUT  505
#define ROW4    (HW_OUT * 16)        // 8080 float4 per (b,h) output row
#define SEGS    16                   // tiles per output row
#define SEG4    512                  // float4 per full tile (32 pixels * 16)
#define TILES   (BATCH * HW_OUT * SEGS)   // 64640
#define SW      40                   // staged floats per input row (32+7, pad 40)

typedef float f32x4 __attribute__((ext_vector_type(4)));

__global__ __launch_bounds__(256) void unfold_tile_kernel(
    const float* __restrict__ in, float* __restrict__ out)
{
    __shared__ float sm[8 * SW];     // 1280 floats = 5 KB

    f32x4* __restrict__ out4 = reinterpret_cast<f32x4*>(out);

    for (int tile = blockIdx.x; tile < TILES; tile += gridDim.x) {
        int bh  = tile >> 4;         // output row index (b*505+h)
        int seg = tile & 15;
        int b   = bh / HW_OUT;
        int h   = bh - b * HW_OUT;
        int w0  = seg << 5;          // first pixel of this tile

        const float* __restrict__ row_base = in + (b * W_IN + h) * W_IN;

        // Stage rows h..h+7, cols w0..w0+39 (clamped) into LDS.
        for (int s = threadIdx.x; s < 8 * SW; s += 256) {
            int r   = s / SW;        // 0..7
            int j   = s - r * SW;    // 0..39
            int col = w0 + j;
            sm[s] = (col < W_IN) ? row_base[(r << 9) + col] : 0.0f;
        }
        __syncthreads();

        // Store phase: read-free from global; dense plain stores.
        int n4 = SEG4;
        if (seg == SEGS - 1) n4 = ROW4 - (SEGS - 1) * SEG4;   // 400 tail
        f32x4* __restrict__ o = out4 + (size_t)bh * ROW4 + seg * SEG4;

        for (int t = threadIdx.x; t < n4; t += 256) {
            int i4 = t & 15;         // float4 within 64-ch pixel
            int p  = t >> 4;         // pixel within tile (0..31)
            int r  = i4 >> 1;        // window row 0..7
            int c  = (i4 & 1) << 2;  // window col base {0,4}

            const float* __restrict__ s = &sm[r * SW + p + c];
            f32x4 v;
            v.x = s[0];
            v.y = s[1];
            v.z = s[2];
            v.w = s[3];
            o[t] = v;                // PLAIN store (dense device-wide stream)
        }
        __syncthreads();             // before next tile overwrites sm
    }
}

extern "C" void kernel_launch(void* const* d_in, const int* in_sizes, int n_in,
                              void* d_out, int out_size, void* d_ws, size_t ws_size,
                              hipStream_t stream)
{
    const float* in  = (const float*)d_in[0];   // (8,512,512,1) f32
    float*       out = (float*)d_out;           // (8,505,505,64) f32

    const int grid = 2048;                      // 8 blocks/CU, 32 waves/CU
    unfold_tile_kernel<<<grid, 256, 0, stream>>>(in, out);
}

// Round 8
// 97.839 us; speedup vs baseline: 1.1653x; 1.1653x over previous
//
#include <hip/hip_runtime.h>

// Reference: out[b,h,w,i] = in[b, h + i/8, w + i%8, 0]
//   in : (8, 512, 512, 1) f32   (8.4 MB)
//   out: (8, 505, 505, 64) f32  (522 MB -> write-BW bound)
//
// Ladder: R2 grid-stride + 4-scalar-load + NT store = 97.4 us (champion)
//         R3 row-block + unaligned-16B-load + NT    = 108.8 us
//         R4 grid-stride + 4-scalar-load + plain    = 143.7 us
//         R5 row-block + 4-scalar-load + NT         = 107.6 us
//         R6 row-block + LDS stage + plain          = 104.2 us
//         R7 tile grid-stride + LDS stage + plain   = 114.0 us
// R8: R2 structure, but each WAVE writes a 4 KB contiguous burst (4 coalesced
// 1 KB NT stores: thread k-th store at base + k*64 + lane), grid 1024 ->
// 4096 long streams instead of 8192 short ones. Probes whether NT write
// throughput is limited by DRAM row-buffer / stream count.

#define HW_OUT  505
#define W_IN    512

typedef float f32x4 __attribute__((ext_vector_type(4)));

__global__ __launch_bounds__(256) void unfold_burst_kernel(
    const float* __restrict__ in, float* __restrict__ out, int total4)
{
    int gtid   = blockIdx.x * blockDim.x + threadIdx.x;
    int wave   = gtid >> 6;
    int lane   = gtid & 63;
    int nwaves = (gridDim.x * blockDim.x) >> 6;

    f32x4* __restrict__ out4 = reinterpret_cast<f32x4*>(out);

    // i4 (which float4 of the 64-ch pixel) is loop-invariant: lane & 15.
    int i4 = lane & 15;
    int r  = i4 >> 1;            // window row 0..7
    int c  = (i4 & 1) << 2;      // window col base {0,4}

    for (int base = wave * 256; base < total4; base += nwaves * 256) {
#pragma unroll
        for (int k = 0; k < 4; ++k) {
            int t = base + k * 64 + lane;    // lanes consecutive per store
            if (t < total4) {
                int pos = t >> 4;            // flat (b, h, w)
                int w   = pos % HW_OUT;
                int tmp = pos / HW_OUT;
                int h   = tmp % HW_OUT;
                int b   = tmp / HW_OUT;

                const float* __restrict__ src =
                    in + ((b * W_IN + h + r) * W_IN + (w + c));

                f32x4 v;
                v.x = src[0];
                v.y = src[1];
                v.z = src[2];
                v.w = src[3];
                __builtin_nontemporal_store(v, out4 + t);
            }
        }
    }
}

extern "C" void kernel_launch(void* const* d_in, const int* in_sizes, int n_in,
                              void* d_out, int out_size, void* d_ws, size_t ws_size,
                              hipStream_t stream)
{
    const float* in  = (const float*)d_in[0];   // (8,512,512,1) f32
    float*       out = (float*)d_out;           // (8,505,505,64) f32

    const int total4 = 8 * HW_OUT * HW_OUT * 16;   // 32,643,200 float4
    const int block  = 256;
    const int grid   = 1024;                       // 4096 waves, 4 KB burst each

    unfold_burst_kernel<<<grid, block, 0, stream>>>(in, out, total4);
}